// Round 8
// baseline (115.870 us; speedup 1.0000x reference)
//
#include <hip/hip_runtime.h>
#include <math.h>

// Problem constants (fixed by the reference)
constexpr int M_ROWS    = 16384;
constexpr int N_PTS     = 16384;
constexpr int MAX_EDGES = 4194304;

constexpr int GD     = 10;                       // cells per dim (cell = R = 0.1)
constexpr int NCELLS = GD * GD * GD;             // 1000
constexpr int NBLK   = N_PTS / 256;              // 64 binning blocks
constexpr int NK     = 27;                       // neighbor cells per query
constexpr int NTH    = NK * M_ROWS;              // 442368
constexpr int KGRID  = NTH / 256;                // 1728 blocks
constexpr int NSCANB = M_ROWS / 256;             // 64 qi-scan blocks

static __device__ __forceinline__ int cell_coord(float v) {
    int c = (int)(v * 10.0f);
    return c < 0 ? 0 : (c > GD - 1 ? GD - 1 : c);
}
static __device__ __forceinline__ int cell_id(float x, float y, float z) {
    return (cell_coord(x) * GD + cell_coord(y)) * GD + cell_coord(z);
}

// K1: per-block cell histograms for BOTH point sets (transposed H[c*64+b]);
// the LAST block additionally converts H to intra-cell block prefixes and
// produces cellStartB/A[0..1000] (exclusive scan of cell totals).
__global__ void __launch_bounds__(256)
hist_kernel(const float* __restrict__ inp, const float* __restrict__ outp,
            int* __restrict__ HB, int* __restrict__ HA,
            int* __restrict__ cellStartB, int* __restrict__ cellStartA,
            int* __restrict__ counter) {
    __shared__ int hb[NCELLS], ha[NCELLS];
    __shared__ int sB[256], sA[256];
    __shared__ int lastflag;
    int b = blockIdx.x, t = threadIdx.x;
    for (int i = t; i < NCELLS; i += 256) { hb[i] = 0; ha[i] = 0; }
    __syncthreads();
    int j = b * 256 + t;
    atomicAdd(&hb[cell_id(inp[j * 3 + 0], inp[j * 3 + 1], inp[j * 3 + 2])], 1);
    atomicAdd(&ha[cell_id(outp[j * 3 + 0], outp[j * 3 + 1], outp[j * 3 + 2])], 1);
    __syncthreads();
    for (int i = t; i < NCELLS; i += 256) {
        HB[i * NBLK + b] = hb[i];
        HA[i * NBLK + b] = ha[i];
    }
    __threadfence();
    if (t == 0) lastflag = (atomicAdd(counter, 1) == NBLK - 1);
    __syncthreads();
    if (!lastflag) return;
    __threadfence();
    // cell scan: thread t owns cells 4t..4t+3 (contiguous 64-int rows in H)
    int tb[4], ta[4];
#pragma unroll
    for (int q = 0; q < 4; ++q) {
        int c = t * 4 + q, rb = 0, ra = 0;
        if (c < NCELLS) {
            for (int k = 0; k < NBLK; ++k) {
                int v = HB[c * NBLK + k]; HB[c * NBLK + k] = rb; rb += v;
            }
            for (int k = 0; k < NBLK; ++k) {
                int v = HA[c * NBLK + k]; HA[c * NBLK + k] = ra; ra += v;
            }
        }
        tb[q] = rb; ta[q] = ra;
    }
    int pb[4], pa[4], rb = 0, ra = 0;
#pragma unroll
    for (int q = 0; q < 4; ++q) { pb[q] = rb; rb += tb[q]; pa[q] = ra; ra += ta[q]; }
    sB[t] = rb; sA[t] = ra;
    __syncthreads();
    for (int off = 1; off < 256; off <<= 1) {
        int vb = (t >= off) ? sB[t - off] : 0;
        int va = (t >= off) ? sA[t - off] : 0;
        __syncthreads();
        sB[t] += vb; sA[t] += va;
        __syncthreads();
    }
    int eb = (t == 0) ? 0 : sB[t - 1];
    int ea = (t == 0) ? 0 : sA[t - 1];
#pragma unroll
    for (int q = 0; q < 4; ++q) {
        int c = t * 4 + q;
        if (c < NCELLS) { cellStartB[c] = eb + pb[q]; cellStartA[c] = ea + pa[q]; }
    }
    if (t == 255) { cellStartB[NCELLS] = sB[255]; cellStartA[NCELLS] = sA[255]; }
}

// K2: stable scatter of both sets (rank = #earlier same-cell points in block,
// via uniform-trip LDS broadcast loop -> deterministic, j-ascending in cell).
// sortedB = {-2x,-2y,-2z,|b|^2}; sortedA = {x,y,z,T-|a|^2}; origin indices kept.
__global__ void __launch_bounds__(256)
scatter_kernel(const float* __restrict__ inp, const float* __restrict__ outp,
               const int* __restrict__ HB, const int* __restrict__ HA,
               const int* __restrict__ cellStartB, const int* __restrict__ cellStartA,
               float4* __restrict__ sortedB, int* __restrict__ sortedJ,
               float4* __restrict__ sortedA, int* __restrict__ sortedRow, float T) {
    __shared__ int scB[256], scA[256];
    int b = blockIdx.x, t = threadIdx.x;
    int j = b * 256 + t;
    float bx = inp[j * 3 + 0], by = inp[j * 3 + 1], bz = inp[j * 3 + 2];
    float qx = outp[j * 3 + 0], qy = outp[j * 3 + 1], qz = outp[j * 3 + 2];
    int cidB = cell_id(bx, by, bz);
    int cidA = cell_id(qx, qy, qz);
    scB[t] = cidB; scA[t] = cidA;
    __syncthreads();
    int rkB = 0, rkA = 0;
    for (int i = 0; i < 255; ++i) {              // uniform trip, broadcast reads
        if (i < t) {
            rkB += (scB[i] == cidB);
            rkA += (scA[i] == cidA);
        }
    }
    float sb2 = __fadd_rn(__fadd_rn(__fmul_rn(bx, bx), __fmul_rn(by, by)), __fmul_rn(bz, bz));
    int posB = cellStartB[cidB] + HB[cidB * NBLK + b] + rkB;
    sortedB[posB] = make_float4(-2.0f * bx, -2.0f * by, -2.0f * bz, sb2);
    sortedJ[posB] = j;
    float sa2 = __fadd_rn(__fadd_rn(__fmul_rn(qx, qx), __fmul_rn(qy, qy)), __fmul_rn(qz, qz));
    int posA = cellStartA[cidA] + HA[cidA * NBLK + b] + rkA;
    sortedA[posA] = make_float4(qx, qy, qz, __fsub_rn(T, sa2));
    sortedRow[posA] = j;
}

// K3: count per (sorted query, neighbor cell). Lanes = consecutive sorted
// queries (~4 cells per wave) -> candidate loads are broadcast within
// same-cell lane groups. Predicate: fma chain <= T-|a|^2 (a.w).
__global__ void __launch_bounds__(256)
count_kernel(const float4* __restrict__ sortedA, const float4* __restrict__ sortedB,
             const int* __restrict__ cellStartB, unsigned char* __restrict__ cnt27) {
    int t = blockIdx.x * 256 + threadIdx.x;
    int k = t >> 14, qi = t & (M_ROWS - 1);
    float4 a = sortedA[qi];
    int cx = cell_coord(a.x) + (k / 9) - 1;
    int cy = cell_coord(a.y) + ((k / 3) % 3) - 1;
    int cz = cell_coord(a.z) + (k % 3) - 1;
    int cnt = 0;
    if (((unsigned)cx < GD) & ((unsigned)cy < GD) & ((unsigned)cz < GD)) {
        int cid = (cx * GD + cy) * GD + cz;
        int s = cellStartB[cid], e = cellStartB[cid + 1];
        for (int p = s; p < e; ++p) {
            float4 q = sortedB[p];
            float v = __fmaf_rn(a.x, q.x, __fmaf_rn(a.y, q.y, __fmaf_rn(a.z, q.z, q.w)));
            cnt += (v <= a.w);
        }
    }
    cnt27[t] = (unsigned char)cnt;
}

// K4: per-sorted-query exclusive scan over 27 counts (u16 prefixes, coalesced)
// + totals scattered to ORIGINAL row order; the LAST block performs the global
// exclusive scan of totals -> row_splits[0..16384].
__global__ void __launch_bounds__(256)
qscan_kernel(const unsigned char* __restrict__ cnt27, unsigned short* __restrict__ cpfx27,
             const int* __restrict__ sortedRow, int* __restrict__ totals,
             int* __restrict__ row_splits, int* __restrict__ counter) {
    __shared__ int sp[256];
    __shared__ int lastflag;
    int t = threadIdx.x;
    int qi = blockIdx.x * 256 + t;
    int sum = 0;
#pragma unroll
    for (int k = 0; k < NK; ++k) {
        cpfx27[k * M_ROWS + qi] = (unsigned short)sum;
        sum += cnt27[k * M_ROWS + qi];
    }
    totals[sortedRow[qi]] = sum;
    __threadfence();                              // release totals
    if (t == 0) lastflag = (atomicAdd(counter, 1) == NSCANB - 1);
    __syncthreads();
    if (!lastflag) return;
    __threadfence();                              // acquire others' totals

    const int4* t4 = (const int4*)totals;
    int s = 0;
#pragma unroll
    for (int i = 0; i < 16; ++i) {
        int4 v = t4[t * 16 + i];
        s += v.x + v.y + v.z + v.w;
    }
    sp[t] = s;
    __syncthreads();
    for (int off = 1; off < 256; off <<= 1) {
        int v = (t >= off) ? sp[t - off] : 0;
        __syncthreads();
        sp[t] += v;
        __syncthreads();
    }
    int cur = (t == 0) ? 0 : sp[t - 1];
#pragma unroll
    for (int i = 0; i < 16; ++i) {
        int4 v = t4[t * 16 + i];
        row_splits[t * 64 + i * 4 + 0] = cur; cur += v.x;
        row_splits[t * 64 + i * 4 + 1] = cur; cur += v.y;
        row_splits[t * 64 + i * 4 + 2] = cur; cur += v.z;
        row_splits[t * 64 + i * 4 + 3] = cur; cur += v.w;
    }
    if (t == 255) row_splits[M_ROWS] = sp[255];
}

// K5: emit (re-test candidates; write original j at rs[origRow]+cpfx27) + tail
// fill of -1 over [E, MAX_EDGES). Per-row order = (k, cell-sorted j):
// deterministic; order freedom validated on-hardware in round 7.
__global__ void __launch_bounds__(256)
emit_fill_kernel(const float4* __restrict__ sortedA, const float4* __restrict__ sortedB,
                 const int* __restrict__ sortedJ, const int* __restrict__ sortedRow,
                 const int* __restrict__ cellStartB, const unsigned short* __restrict__ cpfx27,
                 const int* __restrict__ rs, int* __restrict__ out_idx) {
    int t = blockIdx.x * 256 + threadIdx.x;
    int k = t >> 14, qi = t & (M_ROWS - 1);
    float4 a = sortedA[qi];
    int cx = cell_coord(a.x) + (k / 9) - 1;
    int cy = cell_coord(a.y) + ((k / 3) % 3) - 1;
    int cz = cell_coord(a.z) + (k % 3) - 1;
    if (((unsigned)cx < GD) & ((unsigned)cy < GD) & ((unsigned)cz < GD)) {
        int cid = (cx * GD + cy) * GD + cz;
        int s = cellStartB[cid], e = cellStartB[cid + 1];
        int cur = rs[sortedRow[qi]] + (int)cpfx27[k * M_ROWS + qi];
        for (int p = s; p < e; ++p) {
            float4 q = sortedB[p];
            float v = __fmaf_rn(a.x, q.x, __fmaf_rn(a.y, q.y, __fmaf_rn(a.z, q.z, q.w)));
            if (v <= a.w) out_idx[cur++] = sortedJ[p];
        }
    }
    // Tail fill: [E, MAX_EDGES) <- -1 (disjoint from emit writes < E).
    int E = rs[M_ROWS];
    int total = MAX_EDGES - E;
    if (total > 0) {
        int per = (total + KGRID - 1) / KGRID;
        int s0  = E + blockIdx.x * per;
        int e0  = s0 + per; if (e0 > MAX_EDGES) e0 = MAX_EDGES;
        for (int i = s0 + threadIdx.x; i < e0; i += 256) out_idx[i] = -1;
    }
}

extern "C" void kernel_launch(void* const* d_in, const int* in_sizes, int n_in,
                              void* d_out, int out_size, void* d_ws, size_t ws_size,
                              hipStream_t stream) {
    const float* inp  = (const float*)d_in[0];   // inp_positions [16384,3]
    const float* outp = (const float*)d_in[1];   // out_positions [16384,3]
    int* out_idx    = (int*)d_out;               // [MAX_EDGES]
    int* row_splits = out_idx + MAX_EDGES;       // [M+1]

    char* ws = (char*)d_ws;
    size_t off = 0;
    float4* sortedB = (float4*)(ws + off); off += (size_t)N_PTS * 16;         // 256 KB
    float4* sortedA = (float4*)(ws + off); off += (size_t)M_ROWS * 16;        // 256 KB
    int* sortedJ    = (int*)(ws + off);    off += (size_t)N_PTS * 4;          // 64 KB
    int* sortedRow  = (int*)(ws + off);    off += (size_t)M_ROWS * 4;         // 64 KB
    int* HB         = (int*)(ws + off);    off += (size_t)NCELLS * NBLK * 4;  // 256 KB
    int* HA         = (int*)(ws + off);    off += (size_t)NCELLS * NBLK * 4;  // 256 KB
    int* cellStartB = (int*)(ws + off);    off += 1024 * 4;
    int* cellStartA = (int*)(ws + off);    off += 1024 * 4;
    unsigned char*  cnt27  = (unsigned char*)(ws + off);  off += (size_t)NTH;     // 432 KB
    unsigned short* cpfx27 = (unsigned short*)(ws + off); off += (size_t)NTH * 2; // 864 KB
    int* totals  = (int*)(ws + off); off += (size_t)M_ROWS * 4;               // 64 KB
    int* counter = (int*)(ws + off); off += 256;                              // 2 slots
    if (off > ws_size) return;  // ~2.5 MB; ws is 256 MB

    // T = largest fp32 strictly below (0.1f + 2^-28)^2: d2<=T <=> sqrt(max(d2,0))<=0.1f
    double md = (double)0.1f + ldexp(1.0, -28);
    double m2 = md * md;
    float  T  = (float)m2;
    if ((double)T >= m2) T = nextafterf(T, 0.0f);

    hipMemsetAsync(counter, 0, 8, stream);       // reset both last-block counters
    hist_kernel    <<<dim3(NBLK),  dim3(256), 0, stream>>>(inp, outp, HB, HA, cellStartB, cellStartA, counter);
    scatter_kernel <<<dim3(NBLK),  dim3(256), 0, stream>>>(inp, outp, HB, HA, cellStartB, cellStartA,
                                                           sortedB, sortedJ, sortedA, sortedRow, T);
    count_kernel   <<<dim3(KGRID), dim3(256), 0, stream>>>(sortedA, sortedB, cellStartB, cnt27);
    qscan_kernel   <<<dim3(NSCANB),dim3(256), 0, stream>>>(cnt27, cpfx27, sortedRow, totals, row_splits, counter + 1);
    emit_fill_kernel<<<dim3(KGRID),dim3(256), 0, stream>>>(sortedA, sortedB, sortedJ, sortedRow,
                                                           cellStartB, cpfx27, row_splits, out_idx);
}